// Round 8
// baseline (207.759 us; speedup 1.0000x reference)
//
#include <hip/hip_runtime.h>
#include <hip/hip_cooperative_groups.h>

// Inv2d: B=4, C=128, H=W=64, G=8 (16 ch/grp), K=7, dil=2, pad=6,
// reduce 128->32, span 32->392.
//
// Round 19: single cooperative kernel. R18 instrumentation: red ~2.9us,
// inv ~10.6us (warm), fixed overhead ~71us for 2 kernels vs ~54us for 1
// (R5 fit) -> each kernel boundary costs ~17us of harness overhead. Merge:
// blocks 0..511 run the exact red_gen body (no 8x duplication -- R5's
// mistake), grid.sync(), all 1024 blocks run the exact inv_fused body.
// LDS overlaid via union (32KB max); __launch_bounds__(256,4) caps VGPR
// at 128 so 4 blocks/CU x 256 CU = 1024 co-resident (coop requirement).
// Bit-identical math to R17. Fallback to 2-kernel path if coop launch
// is rejected.

namespace cg = cooperative_groups;

#define HW 4096   // 64*64
#define NC 128
#define NR 32
#define KK 49
#define KSB 144   // bf16 elems per tap: 2 rows x 72 (pad 64->72, 16B-align)

typedef __attribute__((ext_vector_type(8))) short short8;
typedef __attribute__((ext_vector_type(4))) float f32x4;

__device__ __forceinline__ unsigned short f2bf(float f) {
  unsigned int u = __float_as_uint(f);
  u = (u + 0x7fffu + ((u >> 16) & 1u)) >> 16;   // RNE
  return (unsigned short)u;
}
__device__ __forceinline__ float bf2f(unsigned short u) {
  return __uint_as_float(((unsigned int)u) << 16);
}

union SmemU {
  float xs[NC][64];                       // red phase: 32 KB
  struct {
    unsigned short kvs_bf[KK * KSB];      // 13.8 KB
    short wlds[64 * NR];                  // 4 KB
    float bsl[64];
  } inv;
};

// ---- red body: identical math to proven red_gen (R17) ----
__device__ __forceinline__ void red_body(
    SmemU* sm, const float* __restrict__ x,
    const float* __restrict__ w_reduce, const float* __restrict__ b_reduce,
    unsigned short* __restrict__ red_bf, int blk) {
  int t = threadIdx.x;
  int b = blk >> 7;
  int sub = blk & 127;               // row(6b) | ohalf(1b)
  int row = sub >> 1;
  int oh = sub & 1;
  int p0 = row * 64;

  const float* xb = x + b * NC * HW + p0;
  int fx = t & 15;
  int c0 = t >> 4;
#pragma unroll
  for (int r = 0; r < 8; ++r) {
    int c = c0 + 16 * r;
    *(float4*)(&sm->xs[c][fx * 4]) = *(const float4*)(xb + c * HW + fx * 4);
  }
  __syncthreads();

  int px = t & 63;
  int wv = __builtin_amdgcn_readfirstlane(t >> 6);  // wave id 0..3
  int ob = oh * 16 + wv * 4;                        // wave-uniform out base
  const float* wq = w_reduce + ob * NC;             // scalar (s_load) base

  float acc[4];
#pragma unroll
  for (int j = 0; j < 4; ++j) acc[j] = b_reduce[ob + j];

#pragma unroll 8
  for (int k = 0; k < NC; ++k) {
    float xk = sm->xs[k][px];
#pragma unroll
    for (int j = 0; j < 4; ++j) acc[j] += xk * wq[j * NC + k];
  }

  // red^T bf16: [b][px][32 o], one 8B store (o-quad = ob..ob+3)
  union { unsigned long long v; unsigned short u[4]; } pk;
#pragma unroll
  for (int j = 0; j < 4; ++j) pk.u[j] = f2bf(acc[j]);
  *(unsigned long long*)(red_bf + ((size_t)(b * HW) + p0 + px) * NR + ob) = pk.v;
}

// ---- inv body: identical math to proven inv_fused (R17) ----
__device__ __forceinline__ void inv_body(
    SmemU* sm, const float* __restrict__ x,
    const unsigned short* __restrict__ red_bf,
    const float* __restrict__ w_span, const float* __restrict__ b_span,
    float* __restrict__ out, int orig) {
  unsigned short* kvs_bf = sm->inv.kvs_bf;
  short* wlds = sm->inv.wlds;
  float* bsl = sm->inv.bsl;

  int blk = (orig & 7) * 128 + (orig >> 3);   // bijective: 1024 % 8 == 0
  int hp = blk & 31;
  int g = (blk >> 5) & 7;
  int b = blk >> 8;
  int tid = threadIdx.x;
  int h0 = hp * 2;
  int p0 = h0 * 64;                  // this block's 128-px slice

  // ---- stage W_g (fp32 -> bf16) + bias into LDS ----
  const float* wg = w_span + g * KK * NR;            // 1568 floats
#pragma unroll
  for (int it = 0; it < 8; ++it) {
    int idx = it * 256 + tid;
    wlds[idx] = (idx < KK * NR) ? (short)f2bf(wg[idx]) : (short)0;
  }
  if (tid < 64) bsl[tid] = (tid < KK) ? b_span[g * KK + tid] : 0.f;
  __syncthreads();

  int l = tid & 63;
  int wv = __builtin_amdgcn_readfirstlane(tid >> 6);  // wave id 0..3
  int quad = l >> 4;
  int mn = l & 15;

  short8 af[4];
#pragma unroll
  for (int tt = 0; tt < 4; ++tt)
    af[tt] = *(const short8*)(&wlds[(tt * 16 + mn) * NR + quad * 8]);

  f32x4 ci[4];
#pragma unroll
  for (int tt = 0; tt < 4; ++tt) {
#pragma unroll
    for (int r = 0; r < 4; ++r) ci[tt][r] = bsl[tt * 16 + quad * 4 + r];
  }

  const unsigned short* rb =
      red_bf + ((size_t)b * HW + p0 + wv * 32 + mn) * NR + quad * 8;
#pragma unroll
  for (int nt = 0; nt < 2; ++nt) {
    short8 bf = *(const short8*)(rb + (size_t)nt * 16 * NR);
    f32x4 d0 = __builtin_amdgcn_mfma_f32_16x16x32_bf16(af[0], bf, ci[0], 0, 0, 0);
    f32x4 d1 = __builtin_amdgcn_mfma_f32_16x16x32_bf16(af[1], bf, ci[1], 0, 0, 0);
    f32x4 d2 = __builtin_amdgcn_mfma_f32_16x16x32_bf16(af[2], bf, ci[2], 0, 0, 0);
    f32x4 d3 = __builtin_amdgcn_mfma_f32_16x16x32_bf16(af[3], bf, ci[3], 0, 0, 0);
    int pxl = wv * 32 + nt * 16 + mn;          // 0..127 (r is wave-uniform)
    int r = pxl >> 6, col = pxl & 63;
    int base = r * 72 + col;
#pragma unroll
    for (int rg = 0; rg < 4; ++rg) {
      kvs_bf[(0 * 16 + quad * 4 + rg) * KSB + base] = f2bf(d0[rg]);
      kvs_bf[(1 * 16 + quad * 4 + rg) * KSB + base] = f2bf(d1[rg]);
      kvs_bf[(2 * 16 + quad * 4 + rg) * KSB + base] = f2bf(d2[rg]);
    }
    if (quad == 0) kvs_bf[48 * KSB + base] = f2bf(d3[0]);  // only tap 48
  }
  __syncthreads();

  // ---- apply, reading x directly ----
  int c = tid >> 4;                  // channel in group
  int sub = tid & 15;
  int r = sub >> 3;                  // row 0..1
  int oct = sub & 7;                 // col octet

  const float* xc = x + ((size_t)(b * NC + g * 16 + c)) * HW + 8 * oct - 8;
  int mo0 = 0, mo1 = 4, mo4 = 16, mo5 = 20;
  if (oct == 0) { mo0 = 8; mo1 = 12; }
  if (oct == 7) { mo4 = 8; mo5 = 12; }

  float2 a0 = {0.f, 0.f}, a1 = {0.f, 0.f}, a2 = {0.f, 0.f}, a3 = {0.f, 0.f};

#pragma unroll
  for (int i = 0; i < 7; ++i) {
    int rbase = h0 + 2 * i - 6;            // even; rows rbase, rbase+1
    if (rbase < 0 || rbase > 62) continue; // wave-uniform row skip
    const float* pr = xc + (size_t)(rbase + r) * 64;
    float xr[24];
    float4 v;
    v = *(const float4*)(pr + mo0); xr[0]=v.x; xr[1]=v.y; xr[2]=v.z; xr[3]=v.w;
    v = *(const float4*)(pr + mo1); xr[4]=v.x; xr[5]=v.y; xr[6]=v.z; xr[7]=v.w;
    v = *(const float4*)(pr + 8);   xr[8]=v.x; xr[9]=v.y; xr[10]=v.z; xr[11]=v.w;
    v = *(const float4*)(pr + 12);  xr[12]=v.x; xr[13]=v.y; xr[14]=v.z; xr[15]=v.w;
    v = *(const float4*)(pr + mo4); xr[16]=v.x; xr[17]=v.y; xr[18]=v.z; xr[19]=v.w;
    v = *(const float4*)(pr + mo5); xr[20]=v.x; xr[21]=v.y; xr[22]=v.z; xr[23]=v.w;
    if (oct == 0) { xr[2]=0.f; xr[3]=0.f; xr[4]=0.f; xr[5]=0.f; xr[6]=0.f; xr[7]=0.f; }
    if (oct == 7) { xr[16]=0.f; xr[17]=0.f; xr[18]=0.f; xr[19]=0.f; xr[20]=0.f; xr[21]=0.f; }
#pragma unroll
    for (int j = 0; j < 7; ++j) {
      union { short8 v; unsigned short u[8]; } kv;
      kv.v = *(const short8*)(&kvs_bf[(i * 7 + j) * KSB + r * 72 + 8 * oct]);
      a0.x = fmaf(xr[2 + 2 * j], bf2f(kv.u[0]), a0.x);
      a0.y = fmaf(xr[3 + 2 * j], bf2f(kv.u[1]), a0.y);
      a1.x = fmaf(xr[4 + 2 * j], bf2f(kv.u[2]), a1.x);
      a1.y = fmaf(xr[5 + 2 * j], bf2f(kv.u[3]), a1.y);
      a2.x = fmaf(xr[6 + 2 * j], bf2f(kv.u[4]), a2.x);
      a2.y = fmaf(xr[7 + 2 * j], bf2f(kv.u[5]), a2.y);
      a3.x = fmaf(xr[8 + 2 * j], bf2f(kv.u[6]), a3.x);
      a3.y = fmaf(xr[9 + 2 * j], bf2f(kv.u[7]), a3.y);
    }
  }

  int h = h0 + r;
  float* op = out + (size_t)(b * NC + g * 16 + c) * HW + h * 64 + 8 * oct;
  *(float4*)op = make_float4(a0.x, a0.y, a1.x, a1.y);
  *(float4*)(op + 4) = make_float4(a2.x, a2.y, a3.x, a3.y);
}

// ---------------------------------------------------------------- coop kernel
__global__ __launch_bounds__(256, 4) void inv_coop(
    const float* __restrict__ x, const float* __restrict__ w_reduce,
    const float* __restrict__ b_reduce, const float* __restrict__ w_span,
    const float* __restrict__ b_span, unsigned short* __restrict__ red_bf,
    float* __restrict__ out) {
  __shared__ SmemU sm;
  int orig = blockIdx.x;
  if (orig < 512) red_body(&sm, x, w_reduce, b_reduce, red_bf, orig);
  cg::this_grid().sync();
  inv_body(&sm, x, red_bf, w_span, b_span, out, orig);
}

// ---------------------------------------------------------------- fallback kernels
__global__ __launch_bounds__(256) void red_gen(
    const float* __restrict__ x, const float* __restrict__ w_reduce,
    const float* __restrict__ b_reduce, unsigned short* __restrict__ red_bf) {
  __shared__ SmemU sm;
  red_body(&sm, x, w_reduce, b_reduce, red_bf, blockIdx.x);
}

__global__ __launch_bounds__(256) void inv_fused(
    const float* __restrict__ x, const unsigned short* __restrict__ red_bf,
    const float* __restrict__ w_span, const float* __restrict__ b_span,
    float* __restrict__ out) {
  __shared__ SmemU sm;
  inv_body(&sm, x, red_bf, w_span, b_span, out, blockIdx.x);
}

extern "C" void kernel_launch(void* const* d_in, const int* in_sizes, int n_in,
                              void* d_out, int out_size, void* d_ws, size_t ws_size,
                              hipStream_t stream) {
  const float* x        = (const float*)d_in[0];  // [4,128,64,64]
  const float* w_reduce = (const float*)d_in[1];  // [32,128]
  const float* b_reduce = (const float*)d_in[2];  // [32]
  const float* w_span   = (const float*)d_in[3];  // [392,32]
  const float* b_span   = (const float*)d_in[4];  // [392]
  float* out = (float*)d_out;                     // [4,128,64,64]

  unsigned short* red_bf = (unsigned short*)d_ws;  // 4*4096*32 bf16 = 1 MB

  void* args[] = {(void*)&x, (void*)&w_reduce, (void*)&b_reduce,
                  (void*)&w_span, (void*)&b_span, (void*)&red_bf, (void*)&out};
  hipError_t e = hipLaunchCooperativeKernel((void*)inv_coop, dim3(1024),
                                            dim3(256), args, 0, stream);
  if (e != hipSuccess) {
    red_gen<<<512, 256, 0, stream>>>(x, w_reduce, b_reduce, red_bf);
    inv_fused<<<1024, 256, 0, stream>>>(x, red_bf, w_span, b_span, out);
  }
}

// Round 11
// 85.250 us; speedup vs baseline: 2.4371x; 2.4371x over previous
//
#include <hip/hip_runtime.h>

// Inv2d: B=4, C=128, H=W=64, G=8 (16 ch/grp), K=7, dil=2, pad=6,
// reduce 128->32, span 32->392.
//
// Round 22: REVERT to proven R15 source (85.4us, passed, profiled).
// R20/R21's single-row restructure (+launch_bounds(256,5)) failed the
// post-timing divergence tripwire (first call correct, replays wrong);
// source audit found no logic bug -> prime suspect is forced VGPR spill
// (cap 96 vs need 116) interacting with graph replay. Reverting rather
// than re-rolling an unexplained correctness failure.
// Structure: red_gen (grid 512, no x_pad) + inv_fused (grid 1024,
// row-pair blocks, MFMA ker -> fp32 kvs LDS, direct-x apply with
// row-skip + col-mask, bijective XCD swizzle).

#define HW 4096   // 64*64
#define NC 128
#define NR 32
#define KK 49
#define KSTR 136  // apply-loop LDS per-tap stride (2 rows x 68)

typedef __attribute__((ext_vector_type(8))) short short8;
typedef __attribute__((ext_vector_type(4))) float f32x4;

__device__ __forceinline__ unsigned short f2bf(float f) {
  unsigned int u = __float_as_uint(f);
  u = (u + 0x7fffu + ((u >> 16) & 1u)) >> 16;   // RNE
  return (unsigned short)u;
}

// ---------------------------------------------------------------- red_gen
__global__ __launch_bounds__(256) void red_gen(
    const float* __restrict__ x, const float* __restrict__ w_reduce,
    const float* __restrict__ b_reduce, unsigned short* __restrict__ red_bf) {
  // grid: 512 = b(4) x row(64) x ohalf(2). Block: one 64-px row, 16 of 32
  // outputs. Both ohalf blocks stage the same row (2nd read is L2 hit).
  __shared__ float xs[NC][64];       // 32 KB
  int t = threadIdx.x;
  int blk = blockIdx.x;
  int b = blk >> 7;
  int sub = blk & 127;               // row(6b) | ohalf(1b)
  int row = sub >> 1;
  int oh = sub & 1;
  int p0 = row * 64;

  const float* xb = x + b * NC * HW + p0;
  int fx = t & 15;
  int c0 = t >> 4;
#pragma unroll
  for (int r = 0; r < 8; ++r) {
    int c = c0 + 16 * r;
    *(float4*)(&xs[c][fx * 4]) = *(const float4*)(xb + c * HW + fx * 4);
  }
  __syncthreads();

  int px = t & 63;
  int wv = __builtin_amdgcn_readfirstlane(t >> 6);  // wave id 0..3
  int ob = oh * 16 + wv * 4;                        // wave-uniform out base
  const float* wq = w_reduce + ob * NC;             // scalar (s_load) base

  float acc[4];
#pragma unroll
  for (int j = 0; j < 4; ++j) acc[j] = b_reduce[ob + j];

#pragma unroll 8
  for (int k = 0; k < NC; ++k) {
    float xk = xs[k][px];
#pragma unroll
    for (int j = 0; j < 4; ++j) acc[j] += xk * wq[j * NC + k];
  }

  // red^T bf16: [b][px][32 o], one 8B store (o-quad = ob..ob+3)
  union { unsigned long long v; unsigned short u[4]; } pk;
#pragma unroll
  for (int j = 0; j < 4; ++j) pk.u[j] = f2bf(acc[j]);
  *(unsigned long long*)(red_bf + ((size_t)(b * HW) + p0 + px) * NR + ob) = pk.v;
}

// ---------------------------------------------------------------- inv_fused
__global__ __launch_bounds__(256) void inv_fused(
    const float* __restrict__ x, const unsigned short* __restrict__ red_bf,
    const float* __restrict__ w_span, const float* __restrict__ b_span,
    float* __restrict__ out) {
  // grid: 1024 = hpair(32) x g(8) x b(4), XCD-swizzled: each XCD owns 4
  // contiguous (b,g) slices -> x slice stays L2-hot.
  // Phase 1: 4 waves compute ker[49][128px] via MFMA into kvs (fp32).
  // Phase 2: apply loop reading x directly (row skip + col masking).
  __shared__ float kvs[KK * KSTR];   // 26.7 KB
  __shared__ short wlds[64 * NR];    // bf16 W tile, 4 KB (taps 49..63 = 0)
  __shared__ float bsl[64];

  int orig = blockIdx.x;
  int blk = (orig & 7) * 128 + (orig >> 3);   // bijective: 1024 % 8 == 0
  int hp = blk & 31;
  int g = (blk >> 5) & 7;
  int b = blk >> 8;
  int tid = threadIdx.x;
  int h0 = hp * 2;
  int p0 = h0 * 64;                  // this block's 128-px slice

  // ---- stage W_g (fp32 -> bf16) + bias into LDS ----
  const float* wg = w_span + g * KK * NR;            // 1568 floats
#pragma unroll
  for (int it = 0; it < 8; ++it) {
    int idx = it * 256 + tid;
    wlds[idx] = (idx < KK * NR) ? (short)f2bf(wg[idx]) : (short)0;
  }
  if (tid < 64) bsl[tid] = (tid < KK) ? b_span[g * KK + tid] : 0.f;
  __syncthreads();

  int l = tid & 63;
  int wv = __builtin_amdgcn_readfirstlane(tid >> 6);  // wave id 0..3
  int quad = l >> 4;
  int mn = l & 15;

  // A-fragments: A[m=lane&15][k=quad*8+j] (same mapping as proven ker_gen)
  short8 af[4];
#pragma unroll
  for (int tt = 0; tt < 4; ++tt)
    af[tt] = *(const short8*)(&wlds[(tt * 16 + mn) * NR + quad * 8]);

  // bias as MFMA C-operand: C/D row = quad*4+reg, col = lane&15
  f32x4 ci[4];
#pragma unroll
  for (int tt = 0; tt < 4; ++tt) {
#pragma unroll
    for (int r = 0; r < 4; ++r) ci[tt][r] = bsl[tt * 16 + quad * 4 + r];
  }

  // wave wv covers px [p0 + wv*32, +32) in 2 n-tiles of 16 px
  const unsigned short* rb =
      red_bf + ((size_t)b * HW + p0 + wv * 32 + mn) * NR + quad * 8;
#pragma unroll
  for (int nt = 0; nt < 2; ++nt) {
    short8 bf = *(const short8*)(rb + (size_t)nt * 16 * NR);
    f32x4 d0 = __builtin_amdgcn_mfma_f32_16x16x32_bf16(af[0], bf, ci[0], 0, 0, 0);
    f32x4 d1 = __builtin_amdgcn_mfma_f32_16x16x32_bf16(af[1], bf, ci[1], 0, 0, 0);
    f32x4 d2 = __builtin_amdgcn_mfma_f32_16x16x32_bf16(af[2], bf, ci[2], 0, 0, 0);
    f32x4 d3 = __builtin_amdgcn_mfma_f32_16x16x32_bf16(af[3], bf, ci[3], 0, 0, 0);
    int pxl = wv * 32 + nt * 16 + mn;          // 0..127 (r is wave-uniform)
    int r = pxl >> 6, col = pxl & 63;
    float* dst = &kvs[r * 68 + col];
#pragma unroll
    for (int rg = 0; rg < 4; ++rg) {
      dst[(size_t)(0 * 16 + quad * 4 + rg) * KSTR] = d0[rg];
      dst[(size_t)(1 * 16 + quad * 4 + rg) * KSTR] = d1[rg];
      dst[(size_t)(2 * 16 + quad * 4 + rg) * KSTR] = d2[rg];
    }
    if (quad == 0) dst[(size_t)48 * KSTR] = d3[0];  // only tap 48
  }
  __syncthreads();

  // ---- phase 2: apply, reading x directly ----
  int c = tid >> 4;                  // channel in group
  int sub = tid & 15;
  int r = sub >> 3;                  // row 0..1
  int oct = sub & 7;                 // col octet

  // xr[t] holds col (8*oct - 8 + t); FMAs use xr[2..21] (cols 8oct-6..+13)
  const float* xc = x + ((size_t)(b * NC + g * 16 + c)) * HW + 8 * oct - 8;
  // redirect discarded float4 loads (oct 0: cols<0, oct 7: cols>=64) to
  // safe in-row addresses; their xr slots are zeroed below.
  int mo0 = 0, mo1 = 4, mo4 = 16, mo5 = 20;
  if (oct == 0) { mo0 = 8; mo1 = 12; }
  if (oct == 7) { mo4 = 8; mo5 = 12; }

  float2 a0 = {0.f, 0.f}, a1 = {0.f, 0.f}, a2 = {0.f, 0.f}, a3 = {0.f, 0.f};

#pragma unroll
  for (int i = 0; i < 7; ++i) {
    int rbase = h0 + 2 * i - 6;            // even; rows rbase, rbase+1
    if (rbase < 0 || rbase > 62) continue; // wave-uniform row skip
    const float* pr = xc + (size_t)(rbase + r) * 64;
    float xr[24];
    float4 v;
    v = *(const float4*)(pr + mo0); xr[0]=v.x; xr[1]=v.y; xr[2]=v.z; xr[3]=v.w;
    v = *(const float4*)(pr + mo1); xr[4]=v.x; xr[5]=v.y; xr[6]=v.z; xr[7]=v.w;
    v = *(const float4*)(pr + 8);   xr[8]=v.x; xr[9]=v.y; xr[10]=v.z; xr[11]=v.w;
    v = *(const float4*)(pr + 12);  xr[12]=v.x; xr[13]=v.y; xr[14]=v.z; xr[15]=v.w;
    v = *(const float4*)(pr + mo4); xr[16]=v.x; xr[17]=v.y; xr[18]=v.z; xr[19]=v.w;
    v = *(const float4*)(pr + mo5); xr[20]=v.x; xr[21]=v.y; xr[22]=v.z; xr[23]=v.w;
    if (oct == 0) { xr[2]=0.f; xr[3]=0.f; xr[4]=0.f; xr[5]=0.f; xr[6]=0.f; xr[7]=0.f; }
    if (oct == 7) { xr[16]=0.f; xr[17]=0.f; xr[18]=0.f; xr[19]=0.f; xr[20]=0.f; xr[21]=0.f; }
#pragma unroll
    for (int j = 0; j < 7; ++j) {
      const float* kb = &kvs[(i * 7 + j) * KSTR + r * 68 + 8 * oct];
      float4 k0 = *(const float4*)(kb);
      float4 k1 = *(const float4*)(kb + 4);
      a0.x = fmaf(xr[2 + 2 * j], k0.x, a0.x);
      a0.y = fmaf(xr[3 + 2 * j], k0.y, a0.y);
      a1.x = fmaf(xr[4 + 2 * j], k0.z, a1.x);
      a1.y = fmaf(xr[5 + 2 * j], k0.w, a1.y);
      a2.x = fmaf(xr[6 + 2 * j], k1.x, a2.x);
      a2.y = fmaf(xr[7 + 2 * j], k1.y, a2.y);
      a3.x = fmaf(xr[8 + 2 * j], k1.z, a3.x);
      a3.y = fmaf(xr[9 + 2 * j], k1.w, a3.y);
    }
  }

  int h = h0 + r;
  float* op = out + (size_t)(b * NC + g * 16 + c) * HW + h * 64 + 8 * oct;
  *(float4*)op = make_float4(a0.x, a0.y, a1.x, a1.y);
  *(float4*)(op + 4) = make_float4(a2.x, a2.y, a3.x, a3.y);
}

extern "C" void kernel_launch(void* const* d_in, const int* in_sizes, int n_in,
                              void* d_out, int out_size, void* d_ws, size_t ws_size,
                              hipStream_t stream) {
  const float* x        = (const float*)d_in[0];  // [4,128,64,64]
  const float* w_reduce = (const float*)d_in[1];  // [32,128]
  const float* b_reduce = (const float*)d_in[2];  // [32]
  const float* w_span   = (const float*)d_in[3];  // [392,32]
  const float* b_span   = (const float*)d_in[4];  // [392]
  float* out = (float*)d_out;                     // [4,128,64,64]

  unsigned short* red_bf = (unsigned short*)d_ws;  // 4*4096*32 bf16 = 1 MB

  red_gen<<<512, 256, 0, stream>>>(x, w_reduce, b_reduce, red_bf);
  inv_fused<<<1024, 256, 0, stream>>>(x, red_bf, w_span, b_span, out);
}